// Round 16
// baseline (59.158 us; speedup 1.0000x reference)
//
#include <hip/hip_runtime.h>
#include <math.h>

namespace {

constexpr int RAD  = 6;
constexpr int P    = 13;
constexpr int NWIN = 169;   // P*P
constexpr int NTOT = 338;   // 2 refs * NWIN
constexpr int NCH  = 128;
constexpr int NCLS = 32;
constexpr int W    = 64;
constexpr int HW   = 4096;
constexpr float FOUR_LN2 = 2.772588722239781f;

// ---- kernel A tiling: dy-split (h=0: dy 0..6, h=1: dy 7..12) ----
constexpr int TX    = 32;            // pixels per block (half row)
constexpr int CHUNK = 8;             // channels per stage
constexpr int PW    = 48;            // patch width: 44 used + 4 pad
constexpr int FRMAX = CHUNK * 7 * PW;      // 2688 floats (h=0 size)
constexpr int NLD   = 11;            // ceil(2688/256)
constexpr int NCHUNK = NCH / CHUNK;  // 16
constexpr size_t VOLF = (size_t)2 * HW * NTOT;  // floats in volume

__device__ __forceinline__ bool better(float va, int ia, float vb, int ib) {
  return (va > vb) || ((va == vb) && (ia < ib));
}

// ================= Kernel A: correlation volume =================
// 1024 blocks, 256 threads, 4 blocks/CU (LDS ~23.5KB).
// XCD swizzle: XCD k (= blk%8) gets logical lb in [k*128,(k+1)*128) = one
// (ref,b) x 32 consecutive y x both xh x both h -> ~2.5MB working set < L2.
// First 64 blocks also build the label map.
__global__ __launch_bounds__(256, 4) void corr_kernel(
    const float* __restrict__ fr,   // [2][2][128][64][64]  (nref,b,c,y,x)
    const float* __restrict__ ft,   // [2][128][64][64]
    float* __restrict__ vol,
    const int* __restrict__ q,
    int* __restrict__ lab) {
  const int blk = blockIdx.x;
  const int t  = threadIdx.x;

  if (blk < 64) {
    const int idx = blk * 256 + t;
    const int i2b = idx >> 12;
    const int rem = idx & 4095;
    const int y2  = rem >> 6;
    const int x2  = rem & 63;
    lab[idx] = q[(size_t)i2b * 65536 + (y2 * 4) * 256 + x2 * 4];
  }

  // ---- XCD-locality swizzle (bijective: 1024 = 8 * 128) ----
  const int lb = (blk & 7) * 128 + (blk >> 3);
  const int h  = lb & 1;               // dy-half
  const int xh = (lb >> 1) & 1;
  const int y  = (lb >> 2) & 63;
  const int bi = lb >> 8;              // b*2+i
  const int b  = bi >> 1;
  const int ii = bi & 1;
  const int x0 = xh * TX;
  const int cg = t >> 7;               // channel group 0/1
  const int tl = t & 127;

  const int RH    = 7 - h;             // staged rows: 7 (h=0) / 6 (h=1)
  const int yb    = h ? (y + 1) : (y - 6);   // first staged row (logical)
  const int m0    = h * 91;            // m-offset of this half (7*13)
  const int frele = CHUNK * RH * PW;   // 2688 / 2304
  const int msz   = RH * P;            // 91 / 78 outputs per pixel

  __shared__ __align__(16) float smem[2 * FRMAX];       // 21504 B
  __shared__ __align__(16) float ftbuf[2][CHUNK * TX];  // 2048 B

  const int xp  = tl & 15;             // x-pair (2 px)
  const int dyl = tl >> 4;             // 0..7; valid when < RH
  const bool comp = (dyl < RH);

  const float* frbase = fr + (size_t)((ii * 2 + b) * NCH) * HW;
  const float* ftp = ft + (size_t)(b * NCH + (t >> 5)) * HW + y * W + x0 + (t & 31);

  // ---- hoisted staging offsets ----
  int offc[NLD];
  unsigned vmsk = 0u;
  #pragma unroll
  for (int u = 0; u < NLD; ++u) {
    const int e = t + u * 256;
    int o = 0;
    if (e < frele) {
      const int cc  = e / (RH * PW);
      const int rem = e - cc * (RH * PW);
      const int r   = rem / PW;
      const int xc  = rem - r * PW;
      const int yy  = yb + r;
      const int xx  = x0 - RAD + xc;
      if ((unsigned)yy < 64u && (unsigned)xx < 64u && xc < 44) {
        o = cc * HW + yy * W + xx;
        vmsk |= (1u << u);
      }
    }
    offc[u] = o;
  }

  float acc[13][2];
  #pragma unroll
  for (int dx = 0; dx < 13; ++dx) { acc[dx][0] = 0.f; acc[dx][1] = 0.f; }

  float rg[NLD];
  float rft;

  auto stage_load = [&](int c0) {
    const float* fb = frbase + (size_t)c0 * HW;
    #pragma unroll
    for (int u = 0; u < NLD; ++u) {
      const float v = fb[offc[u]];
      rg[u] = (vmsk & (1u << u)) ? v : 0.f;
    }
    rft = ftp[(size_t)c0 * HW];
  };
  auto stage_write = [&](int s) {
    float* frb = smem + s * FRMAX;
    #pragma unroll
    for (int u = 0; u < NLD; ++u) {
      const int e = t + u * 256;
      if (e < frele) frb[e] = rg[u];
    }
    ftbuf[s][t] = rft;
  };

  stage_load(0);
  stage_write(0);
  __syncthreads();

  for (int k = 0; k < NCHUNK; ++k) {
    const int cur = k & 1;
    if (k < NCHUNK - 1) stage_load((k + 1) * CHUNK);
    if (comp) {
      const float* frb = smem + cur * FRMAX;
      #pragma unroll
      for (int c2 = 0; c2 < 4; ++c2) {
        const int cc = cg * 4 + c2;
        const float* fp = frb + (cc * RH + dyl) * PW + xp * 2;
        float w[14];
        #pragma unroll
        for (int j = 0; j < 14; ++j) w[j] = fp[j];
        const float2 tq = *(const float2*)(&ftbuf[cur][cc * TX + xp * 2]);
        #pragma unroll
        for (int dx = 0; dx < 13; ++dx) {
          acc[dx][0] = fmaf(w[dx    ], tq.x, acc[dx][0]);
          acc[dx][1] = fmaf(w[dx + 1], tq.y, acc[dx][1]);
        }
      }
    }
    // R9-proven single-barrier double-buffer schedule.
    if (k < NCHUNK - 1) stage_write(cur ^ 1);
    __syncthreads();
  }

  // --- cross-cg reduction (staging LDS dead) ---
  if (comp && cg == 1) {
    float* rb = smem + tl * 26;
    #pragma unroll
    for (int dx = 0; dx < 13; ++dx) {
      rb[dx * 2]     = acc[dx][0];
      rb[dx * 2 + 1] = acc[dx][1];
    }
  }
  __syncthreads();
  if (comp && cg == 0) {
    const float* rb = smem + tl * 26;
    #pragma unroll
    for (int dx = 0; dx < 13; ++dx) {
      acc[dx][0] += rb[dx * 2];
      acc[dx][1] += rb[dx * 2 + 1];
    }
  }
  __syncthreads();
  // --- transpose to tile[px][m_local] (overlays dead reduction area) ---
  if (comp && cg == 0) {
    #pragma unroll
    for (int dx = 0; dx < 13; ++dx) {
      smem[(xp * 2    ) * msz + dyl * P + dx] = acc[dx][0];
      smem[(xp * 2 + 1) * msz + dyl * P + dx] = acc[dx][1];
    }
  }
  __syncthreads();
  // --- store: 32 runs of msz consecutive floats ---
  {
    const int tot = TX * msz;
    float* gb = vol + ((size_t)(b * HW + y * W + x0) * 2 + ii) * NWIN + m0;
    for (int e = t; e < tot; e += 256) {
      const int px = e / msz;
      const int m  = e - px * msz;
      gb[(size_t)px * (2 * NWIN) + m] = smem[e];
    }
  }
}

// ================= Kernel B: wave-per-pixel post-processing =================
__global__ __launch_bounds__(256) void post_kernel(
    const float* __restrict__ vol,  // [pix][2][169]
    const int*  __restrict__ lab,   // [4][64][64]
    float* __restrict__ out) {      // [2][32][64][64]
  const int blk  = blockIdx.x;
  const int t    = threadIdx.x;
  const int w    = t >> 6;
  const int lane = t & 63;
  const int pix  = blk * 4 + w;
  const int b = pix >> 12;
  const int y = (pix >> 6) & 63;
  const int x = pix & 63;

  __shared__ float accS[4][NCLS];
  accS[w][lane & 31] = 0.f;

  float vv[6];
  float lmax = -INFINITY;
  const float* vp = vol + (size_t)pix * NTOT;
  #pragma unroll
  for (int k = 0; k < 6; ++k) {
    const int e = lane + 64 * k;
    vv[k] = (e < NTOT) ? vp[e] : -INFINITY;
    lmax = fmaxf(lmax, vv[k]);
  }
  #pragma unroll
  for (int off = 32; off > 0; off >>= 1)
    lmax = fmaxf(lmax, __shfl_xor(lmax, off));

  float p[6];
  float lsum = 0.f;
  #pragma unroll
  for (int k = 0; k < 6; ++k) {
    const int e = lane + 64 * k;
    p[k] = (e < NTOT) ? __expf(vv[k] - lmax) : 0.f;
    lsum += p[k];
  }
  #pragma unroll
  for (int off = 32; off > 0; off >>= 1)
    lsum += __shfl_xor(lsum, off);
  const float rinv = 1.f / lsum;
  #pragma unroll
  for (int k = 0; k < 6; ++k) p[k] *= rinv;

  float a1_0 = -1.f, a2_0 = -1.f, a1_1 = -1.f, a2_1 = -1.f;
  int   j1_0 = 1 << 20, j2_0 = 1 << 20, j1_1 = 1 << 20, j2_1 = 1 << 20;
  #pragma unroll
  for (int k = 0; k < 6; ++k) {
    const int e = lane + 64 * k;
    if (e < NTOT) {
      const int r = (e >= NWIN) ? 1 : 0;
      const int m = e - r * NWIN;
      const float pv = p[k];
      if (r == 0) {
        if (better(pv, m, a1_0, j1_0)) { a2_0 = a1_0; j2_0 = j1_0; a1_0 = pv; j1_0 = m; }
        else if (better(pv, m, a2_0, j2_0)) { a2_0 = pv; j2_0 = m; }
      } else {
        if (better(pv, m, a1_1, j1_1)) { a2_1 = a1_1; j2_1 = j1_1; a1_1 = pv; j1_1 = m; }
        else if (better(pv, m, a2_1, j2_1)) { a2_1 = pv; j2_1 = m; }
      }
    }
  }
  #pragma unroll
  for (int off = 32; off > 0; off >>= 1) {
    {
      const float u1 = __shfl_xor(a1_0, off); const int q1 = __shfl_xor(j1_0, off);
      const float u2 = __shfl_xor(a2_0, off); const int q2 = __shfl_xor(j2_0, off);
      if (better(u1, q1, a1_0, j1_0)) {
        float nv2; int ni2;
        if (better(a1_0, j1_0, u2, q2)) { nv2 = a1_0; ni2 = j1_0; }
        else                            { nv2 = u2;   ni2 = q2; }
        a1_0 = u1; j1_0 = q1; a2_0 = nv2; j2_0 = ni2;
      } else if (better(u1, q1, a2_0, j2_0)) { a2_0 = u1; j2_0 = q1; }
    }
    {
      const float u1 = __shfl_xor(a1_1, off); const int q1 = __shfl_xor(j1_1, off);
      const float u2 = __shfl_xor(a2_1, off); const int q2 = __shfl_xor(j2_1, off);
      if (better(u1, q1, a1_1, j1_1)) {
        float nv2; int ni2;
        if (better(a1_1, j1_1, u2, q2)) { nv2 = a1_1; ni2 = j1_1; }
        else                            { nv2 = u2;   ni2 = q2; }
        a1_1 = u1; j1_1 = q1; a2_1 = nv2; j2_1 = ni2;
      } else if (better(u1, q1, a2_1, j2_1)) { a2_1 = u1; j2_1 = q1; }
    }
  }

  const float e10 = __expf(a1_0), e20 = __expf(a2_0);
  const float rs0 = 1.f / (e10 + e20);
  const float w00 = e10 * rs0, w10 = e20 * rs0;
  const bool  fl0 = (a1_0 > 0.1f);
  const float xs00 = (float)(j1_0 % P), ys00 = (float)(j1_0 / P);
  const float xs10 = (float)(j2_0 % P), ys10 = (float)(j2_0 / P);

  const float e11 = __expf(a1_1), e21 = __expf(a2_1);
  const float rs1 = 1.f / (e11 + e21);
  const float w01 = e11 * rs1, w11 = e21 * rs1;
  const bool  fl1 = (a1_1 > 0.1f);
  const float xs01 = (float)(j1_1 % P), ys01 = (float)(j1_1 / P);
  const float xs11 = (float)(j2_1 % P), ys11 = (float)(j2_1 / P);

  #pragma unroll
  for (int k = 0; k < 6; ++k) {
    const int e = lane + 64 * k;
    if (e < NTOT) {
      const int r  = (e >= NWIN) ? 1 : 0;
      const int m  = e - r * NWIN;
      const int dy = m / P;
      const int dx = m - dy * P;
      const bool  fl = r ? fl1 : fl0;
      float val;
      if (fl) {
        const float wA = r ? w01 : w00, wB = r ? w11 : w10;
        const float xA = r ? xs01 : xs00, yA = r ? ys01 : ys00;
        const float xB = r ? xs11 : xs10, yB = r ? ys11 : ys10;
        const float fdx0 = (float)dx - xA, fdy0 = (float)dy - yA;
        const float fdx1 = (float)dx - xB, fdy1 = (float)dy - yB;
        val = wA * __expf(-FOUR_LN2 * (fdx0 * fdx0 + fdy0 * fdy0))
            + wB * __expf(-FOUR_LN2 * (fdx1 * fdx1 + fdy1 * fdy1));
      } else {
        val = p[k];
      }
      const int yy = y + dy - RAD;
      const int xx = x + dx - RAD;
      if ((unsigned)yy < 64u && (unsigned)xx < 64u) {
        const int cls = lab[(size_t)(r * 2 + b) * 4096 + yy * W + xx];
        atomicAdd(&accS[w][cls], val);
      }
    }
  }
  __syncthreads();

  if (t < 4 * NCLS) {
    const int cls = t >> 2;
    const int j   = t & 3;
    const int x0  = (blk * 4) & 63;
    const float sc = (cls == 0) ? 1.0f : 1.15f;
    out[(size_t)(b * NCLS + cls) * HW + y * W + x0 + j] = accS[j][cls] * sc;
  }
}

}  // namespace

extern "C" void kernel_launch(void* const* d_in, const int* in_sizes, int n_in,
                              void* d_out, int out_size, void* d_ws, size_t ws_size,
                              hipStream_t stream) {
  const float* fr = (const float*)d_in[0];   // feats_r
  const float* ft = (const float*)d_in[1];   // feats_t
  const int*   q  = (const int*)d_in[2];     // quantized_r
  float* out = (float*)d_out;
  float* vol = (float*)d_ws;                                   // 11,075,584 B
  int*   lab = (int*)((char*)d_ws + VOLF * sizeof(float));     // +64 KB

  corr_kernel<<<dim3(2 * 2 * 64 * 2 * 2), dim3(256), 0, stream>>>(fr, ft, vol, q, lab);
  post_kernel<<<dim3(2 * HW / 4), dim3(256), 0, stream>>>(vol, lab, out);
}